// Round 1
// baseline (2700.173 us; speedup 1.0000x reference)
//
#include <hip/hip_runtime.h>

// GRAPH_MAMBA: bidirectional mamba (3 layers) + FFN + chebyshev graph conv
// with per-node pooled weights. All fp32 this round (correctness baseline).
//
// Shapes: B=16 N=512 D=256 DI=512 S=R=16 H=512 E=10 K=3 P=96, M = B*N = 8192.

#define B_  16
#define N_  512
#define D_  256
#define DI_ 512
#define S_  16
#define M_  8192
#define H_  512
#define E_  10
#define P_  96

__device__ __forceinline__ float silu_f(float x) { return x / (1.f + __expf(-x)); }
__device__ __forceinline__ float softplus_f(float x) {
  return (x > 20.f) ? x : log1pf(__expf(x));
}

// ---------------------------------------------------------------- LayerNorm
// one wave per row of 256; block = 4 rows
__global__ __launch_bounds__(256) void ln_kernel(
    const float* __restrict__ x, const float* __restrict__ g,
    const float* __restrict__ b, float* __restrict__ out) {
  int w = threadIdx.x >> 6, lane = threadIdx.x & 63;
  long row = (long)blockIdx.x * 4 + w;
  float4 v = *(const float4*)(x + row * 256 + lane * 4);
  float s  = v.x + v.y + v.z + v.w;
  float sq = v.x*v.x + v.y*v.y + v.z*v.z + v.w*v.w;
#pragma unroll
  for (int off = 32; off >= 1; off >>= 1) {
    s  += __shfl_xor(s, off);
    sq += __shfl_xor(sq, off);
  }
  float mean = s * (1.f / 256.f);
  float var  = sq * (1.f / 256.f) - mean * mean;
  float rs   = rsqrtf(var + 1e-5f);
  float4 gv = *(const float4*)(g + lane * 4);
  float4 bv = *(const float4*)(b + lane * 4);
  float4 o;
  o.x = (v.x - mean) * rs * gv.x + bv.x;
  o.y = (v.y - mean) * rs * gv.y + bv.y;
  o.z = (v.z - mean) * rs * gv.z + bv.z;
  o.w = (v.w - mean) * rs * gv.w + bv.w;
  *(float4*)(out + row * 256 + lane * 4) = o;
}

// ---------------------------------------------------------------- GEMM
// C = act(scale * A@W [- I] [+ bias]) [+ Cin],  64x64 tile, 4x4/thread.
// A: M x K (row stride ldA), optional per-batch row flip (NB rows/batch),
// optional silu-gate pair G (A_eff = A * silu(G)). W: K x Nc row-major.
// M % 64 == 0, K % 16 == 0, Nc % 4 == 0 required (true for all uses here).
__global__ __launch_bounds__(256) void gemm_k(
    const float* __restrict__ A, int ldA, long sAz,
    const float* __restrict__ G, int ldG,
    const float* __restrict__ W, long sWz,
    const float* __restrict__ bias,
    const float* __restrict__ Cin,
    float* __restrict__ Cout, long sCz,
    int M, int K, int Nc,
    int flipA, int flipOut, int NB,
    int act, float scale, int subIdent) {
  __shared__ float As[16][68];
  __shared__ float Bs[16][68];
  int z = blockIdx.z;
  A += sAz * z; W += sWz * z; Cout += sCz * z;
  if (G) G += sAz * z;
  const int tid = threadIdx.x;
  const int tn = tid & 15, tm = tid >> 4;
  const int n0 = blockIdx.x << 6, m0 = blockIdx.y << 6;
  float acc[4][4] = {};
  const int mlA = tid >> 2, kqA = (tid & 3) << 2;
  int rowA = m0 + mlA;
  if (flipA) { int t = rowA % NB; rowA += (NB - 1 - 2 * t); }
  const int klB = tid >> 4, nqB = (tid & 15) << 2;
  const int nB = n0 + nqB;

  for (int k0 = 0; k0 < K; k0 += 16) {
    float4 av = *(const float4*)(A + (long)rowA * ldA + k0 + kqA);
    if (G) {
      float4 gv = *(const float4*)(G + (long)rowA * ldG + k0 + kqA);
      av.x *= silu_f(gv.x); av.y *= silu_f(gv.y);
      av.z *= silu_f(gv.z); av.w *= silu_f(gv.w);
    }
    As[kqA + 0][mlA] = av.x; As[kqA + 1][mlA] = av.y;
    As[kqA + 2][mlA] = av.z; As[kqA + 3][mlA] = av.w;
    float4 bv = make_float4(0.f, 0.f, 0.f, 0.f);
    if (nB < Nc) bv = *(const float4*)(W + (long)(k0 + klB) * Nc + nB);
    *(float4*)&Bs[klB][nqB] = bv;
    __syncthreads();
#pragma unroll
    for (int kk = 0; kk < 16; ++kk) {
      float4 a4 = *(const float4*)&As[kk][tm << 2];
      float4 b4 = *(const float4*)&Bs[kk][tn << 2];
      float aa[4] = {a4.x, a4.y, a4.z, a4.w};
      float bb[4] = {b4.x, b4.y, b4.z, b4.w};
#pragma unroll
      for (int i = 0; i < 4; ++i)
#pragma unroll
        for (int j = 0; j < 4; ++j)
          acc[i][j] = fmaf(aa[i], bb[j], acc[i][j]);
    }
    __syncthreads();
  }

#pragma unroll
  for (int i = 0; i < 4; ++i) {
    int m = m0 + (tm << 2) + i;
    int rowO = m;
    if (flipOut) { int t = m % NB; rowO += (NB - 1 - 2 * t); }
#pragma unroll
    for (int j = 0; j < 4; ++j) {
      int n = n0 + (tn << 2) + j;
      if (n >= Nc) continue;
      float v = acc[i][j] * scale;
      if (subIdent && m == n) v -= 1.f;
      if (bias) v += bias[n];
      if (act == 1) v = silu_f(v);
      if (Cin) v += Cin[(long)rowO * Nc + n];
      Cout[(long)rowO * Nc + n] = v;
    }
  }
}

// ---------------------------------------------------------------- causal conv4
// xc[b,t,di] = silu( sum_j xi[b,t+j-3,di]*cw[di,j] + cb[di] ); xi = xz[...,:512]
__global__ __launch_bounds__(256) void conv_kernel(
    const float* __restrict__ xz, const float* __restrict__ cw,
    const float* __restrict__ cb, float* __restrict__ xc) {
  int dir = blockIdx.x >> 1;
  int di  = ((blockIdx.x & 1) << 8) + threadIdx.x;
  int t = blockIdx.y, b = blockIdx.z;
  long rbase = (long)dir * M_ + (long)b * N_;
  float acc = cb[dir * DI_ + di];
#pragma unroll
  for (int j = 0; j < 4; ++j) {
    int tp = t + j - 3;
    if (tp >= 0)
      acc += xz[(rbase + tp) * 1024 + di] * cw[(dir * DI_ + di) * 4 + j];
  }
  xc[(rbase + t) * DI_ + di] = silu_f(acc);
}

// ---------------------------------------------------------------- dt projection
// dt[m,di] = softplus( dbc[m, 0:16] @ Wd[:,di] + bd[di] )
__global__ __launch_bounds__(256) void dt_kernel(
    const float* __restrict__ dbc, const float* __restrict__ Wd,
    const float* __restrict__ bd, float* __restrict__ dt) {
  int dir = blockIdx.z;
  long m = blockIdx.y;
  int di = (blockIdx.x << 8) + threadIdx.x;
  const float* dr = dbc + (dir * (long)M_ + m) * 48;
  const float* wp = Wd + dir * (16 * DI_) + di;
  float acc = bd[dir * DI_ + di];
#pragma unroll
  for (int r = 0; r < 16; ++r) acc += dr[r] * wp[r * DI_];
  dt[(dir * (long)M_ + m) * DI_ + di] = softplus_f(acc);
}

// ---------------------------------------------------------------- selective scan
// block: b fixed, 16 di x 16 s lanes. Stages 16 timesteps to LDS per chunk.
__global__ __launch_bounds__(256) void scan_kernel(
    const float* __restrict__ dt, const float* __restrict__ xc,
    const float* __restrict__ dbc, const float* __restrict__ A_log,
    const float* __restrict__ D_skip, float* __restrict__ y) {
  int dir = blockIdx.z, b = blockIdx.y;
  int di0 = blockIdx.x << 4;
  int s = threadIdx.x & 15, dl = threadIdx.x >> 4;
  int di = di0 + dl;
  float nA = -__expf(A_log[((long)dir * DI_ + di) * S_ + s]);
  float h = 0.f;
  __shared__ float s_dt[16][17], s_xc[16][17], s_B[16][17], s_C[16][17], s_y[16][17];
  long rbase = (long)dir * M_ + (long)b * N_;
  float Dv_w = D_skip[dir * DI_ + di0 + s];  // write phase uses di index = s

  for (int t0 = 0; t0 < N_; t0 += 16) {
    long r = rbase + t0 + dl;   // staging: timestep = dl, element = s
    s_dt[dl][s] = dt[r * DI_ + di0 + s];
    s_xc[dl][s] = xc[r * DI_ + di0 + s];
    s_B[dl][s]  = dbc[r * 48 + 16 + s];
    s_C[dl][s]  = dbc[r * 48 + 32 + s];
    __syncthreads();
#pragma unroll
    for (int tt = 0; tt < 16; ++tt) {
      float dtv = s_dt[tt][dl];
      float xcv = s_xc[tt][dl];
      float dA = __expf(dtv * nA);
      h = fmaf(dA, h, dtv * xcv * s_B[tt][s]);
      float p = h * s_C[tt][s];
      p += __shfl_xor(p, 1); p += __shfl_xor(p, 2);
      p += __shfl_xor(p, 4); p += __shfl_xor(p, 8);
      if (s == 0) s_y[tt][dl] = p;
    }
    __syncthreads();
    y[r * DI_ + di0 + s] = s_y[dl][s] + s_xc[dl][s] * Dv_w;
    __syncthreads();
  }
}

// ---------------------------------------------------------------- sup = softmax(relu(emb emb^T))
__global__ __launch_bounds__(256) void sup_kernel(
    const float* __restrict__ emb, float* __restrict__ sup) {
  __shared__ float se[N_ * E_];
  __shared__ float red[4];
  for (int i = threadIdx.x; i < N_ * E_; i += 256) se[i] = emb[i];
  __syncthreads();
  int i = blockIdx.x;
  const float* ei = &se[i * E_];
  float v[2];
#pragma unroll
  for (int q = 0; q < 2; ++q) {
    int j = threadIdx.x + q * 256;
    const float* ej = &se[j * E_];
    float d = 0.f;
#pragma unroll
    for (int e = 0; e < E_; ++e) d += ei[e] * ej[e];
    v[q] = fmaxf(d, 0.f);
  }
  int w = threadIdx.x >> 6, lane = threadIdx.x & 63;
  float mx = fmaxf(v[0], v[1]);
#pragma unroll
  for (int off = 32; off >= 1; off >>= 1) mx = fmaxf(mx, __shfl_xor(mx, off));
  if (lane == 0) red[w] = mx;
  __syncthreads();
  mx = fmaxf(fmaxf(red[0], red[1]), fmaxf(red[2], red[3]));
  __syncthreads();
  float e0 = __expf(v[0] - mx), e1 = __expf(v[1] - mx);
  float sm = e0 + e1;
#pragma unroll
  for (int off = 32; off >= 1; off >>= 1) sm += __shfl_xor(sm, off);
  if (lane == 0) red[w] = sm;
  __syncthreads();
  float inv = 1.f / (red[0] + red[1] + red[2] + red[3]);
  sup[(long)i * N_ + threadIdx.x] = e0 * inv;
  sup[(long)i * N_ + threadIdx.x + 256] = e1 * inv;
}

// ---------------------------------------------------------------- Wn chunk gen
// Wn[nl,kd,o] = sum_e emb[n0+nl,e] * pool[e,kd,o]   (kd = k*256+d, 768 total)
__global__ __launch_bounds__(256) void wn_chunk_kernel(
    const float* __restrict__ emb, const float* __restrict__ pool,
    float* __restrict__ Wn, int n0) {
  int kd = blockIdx.x;   // 0..767
  int nl = blockIdx.y;   // 0..63
  int o = threadIdx.x;
  const float* er = emb + (n0 + nl) * E_;
  float acc = 0.f;
#pragma unroll
  for (int e = 0; e < E_; ++e)
    acc = fmaf(er[e], pool[((long)e * 768 + kd) * 256 + o], acc);
  Wn[((long)nl * 768 + kd) * 256 + o] = acc;
}

// ---------------------------------------------------------------- apply Wn
// x2[b,n,o] = sum_kd xg_cat[b,n,kd]*Wn[n,kd,o] + (emb @ bias_pool)[n,o]
// block: one n, one o-quarter (64 o), 4 b-groups of 4.
__global__ __launch_bounds__(256) void apply_wn_kernel(
    const float* __restrict__ x, const float* __restrict__ xg1,
    const float* __restrict__ xg2, const float* __restrict__ Wn,
    const float* __restrict__ emb, const float* __restrict__ bias_pool,
    float* __restrict__ x2, int n0) {
  __shared__ float xg[16][772];
  int nl = blockIdx.y;
  int n = n0 + nl;
  int o = (blockIdx.x << 6) + (threadIdx.x & 63);
  int bg = threadIdx.x >> 6;
  for (int i = threadIdx.x; i < 16 * 768; i += 256) {
    int b = i / 768, kd = i - b * 768;
    int k = kd >> 8, d = kd & 255;
    const float* src = (k == 0) ? x : (k == 1) ? xg1 : xg2;
    xg[b][kd] = src[((long)b * N_ + n) * D_ + d];
  }
  __syncthreads();
  float acc0 = 0.f, acc1 = 0.f, acc2 = 0.f, acc3 = 0.f;
  const float* wr = Wn + (long)nl * 768 * 256 + o;
  const float* xr = &xg[bg * 4][0];
#pragma unroll 4
  for (int kd = 0; kd < 768; ++kd) {
    float w = wr[(long)kd * 256];
    acc0 = fmaf(xr[kd], w, acc0);
    acc1 = fmaf(xr[772 + kd], w, acc1);
    acc2 = fmaf(xr[2 * 772 + kd], w, acc2);
    acc3 = fmaf(xr[3 * 772 + kd], w, acc3);
  }
  float bsum = 0.f;
#pragma unroll
  for (int e = 0; e < E_; ++e) bsum = fmaf(emb[n * E_ + e], bias_pool[e * 256 + o], bsum);
  int b0 = bg * 4;
  x2[((long)(b0 + 0) * N_ + n) * D_ + o] = acc0 + bsum;
  x2[((long)(b0 + 1) * N_ + n) * D_ + o] = acc1 + bsum;
  x2[((long)(b0 + 2) * N_ + n) * D_ + o] = acc2 + bsum;
  x2[((long)(b0 + 3) * N_ + n) * D_ + o] = acc3 + bsum;
}

// ---------------------------------------------------------------- launcher
static inline void gemm(hipStream_t st,
                        const float* A, int ldA, long sAz,
                        const float* G, int ldG,
                        const float* W, long sWz,
                        const float* bias, const float* Cin,
                        float* Cout, long sCz,
                        int M, int K, int Nc,
                        int flipA, int flipOut, int NB,
                        int act, float scale, int subIdent, int batch) {
  dim3 g((Nc + 63) / 64, M / 64, batch);
  gemm_k<<<g, 256, 0, st>>>(A, ldA, sAz, G, ldG, W, sWz, bias, Cin, Cout, sCz,
                            M, K, Nc, flipA, flipOut, NB, act, scale, subIdent);
}

extern "C" void kernel_launch(void* const* d_in, const int* in_sizes, int n_in,
                              void* d_out, int out_size, void* d_ws, size_t ws_size,
                              hipStream_t stream) {
  (void)in_sizes; (void)n_in; (void)out_size; (void)ws_size;
  const float* input_  = (const float*)d_in[0];
  const float* ln1_g   = (const float*)d_in[1];
  const float* ln1_b   = (const float*)d_in[2];
  const float* ln2_g   = (const float*)d_in[3];
  const float* ln2_b   = (const float*)d_in[4];
  const float* W_in    = (const float*)d_in[5];   // (2,256,1024)
  const float* conv_w  = (const float*)d_in[6];   // (2,512,4)
  const float* conv_b  = (const float*)d_in[7];   // (2,512)
  const float* W_xproj = (const float*)d_in[8];   // (2,512,48)
  const float* W_dt    = (const float*)d_in[9];   // (2,16,512)
  const float* b_dt    = (const float*)d_in[10];  // (2,512)
  const float* A_log   = (const float*)d_in[11];  // (2,512,16)
  const float* D_skip  = (const float*)d_in[12];  // (2,512)
  const float* W_out   = (const float*)d_in[13];  // (2,512,256)
  const float* ffn_W1  = (const float*)d_in[14];  // (256,512)
  const float* ffn_b1  = (const float*)d_in[15];
  const float* ffn_W2  = (const float*)d_in[16];  // (512,256)
  const float* ffn_b2  = (const float*)d_in[17];
  const float* node_emb    = (const float*)d_in[18]; // (512,10)
  const float* weights_pool= (const float*)d_in[19]; // (10,3,256,256)
  const float* bias_pool   = (const float*)d_in[20]; // (10,256)
  const float* W_proj  = (const float*)d_in[21];  // (256,96)
  const float* b_proj  = (const float*)d_in[22];  // (96,)
  float* out = (float*)d_out;

  float* ws = (float*)d_ws;
  // arena (floats)
  float* x    = ws;                       // 2,097,152
  float* xn   = x + 2097152;              // 2,097,152
  float* xzB  = xn + 2097152;             // 16,777,216  (2 dirs x M x 1024)
  float* xcB  = xzB + 16777216;           // 8,388,608   (2 x M x 512)
  float* dbcB = xcB + 8388608;            // 786,432     (2 x M x 48)
  float* dtB  = dbcB + 786432;            // 8,388,608
  float* yB   = dtB + 8388608;            // 8,388,608
  // graph-stage aliases (mamba buffers are dead by then)
  float* hB    = xzB;                     // FFN hidden (alias; z consumed first)
  float* supB  = dbcB;                    // 262,144
  float* chebB = dbcB + 262144;           // 262,144
  float* xg1   = xcB;                     // 2,097,152
  float* xg2   = xcB + 2097152;           // 2,097,152
  float* WnB   = xzB;                     // 12,582,912 (chunk of 64 nodes)
  float* x2B   = dtB;                     // 2,097,152

  const float* xsrc = input_;
  for (int L = 0; L < 3; ++L) {
    // LN1
    ln_kernel<<<2048, 256, 0, stream>>>(xsrc, ln1_g, ln1_b, xn);
    // in_proj per dir (dir1 reads xn with per-batch row flip)
    for (int dir = 0; dir < 2; ++dir)
      gemm(stream, xn, 256, 0, nullptr, 0,
           W_in + (long)dir * 256 * 1024, 0, nullptr, nullptr,
           xzB + (long)dir * M_ * 1024, 0,
           M_, 256, 1024, dir, 0, N_, 0, 1.f, 0, 1);
    // conv (both dirs)
    conv_kernel<<<dim3(4, N_, B_), 256, 0, stream>>>(xzB, conv_w, conv_b, xcB);
    // x-projection -> dbc (dt_raw | B | C)
    for (int dir = 0; dir < 2; ++dir)
      gemm(stream, xcB + (long)dir * M_ * 512, 512, 0, nullptr, 0,
           W_xproj + (long)dir * 512 * 48, 0, nullptr, nullptr,
           dbcB + (long)dir * M_ * 48, 0,
           M_, 512, 48, 0, 0, N_, 0, 1.f, 0, 1);
    // dt = softplus(dbc[:,:16] @ W_dt + b_dt)
    dt_kernel<<<dim3(2, M_, 2), 256, 0, stream>>>(dbcB, W_dt, b_dt, dtB);
    // selective scan (both dirs)
    scan_kernel<<<dim3(32, B_, 2), 256, 0, stream>>>(dtB, xcB, dbcB, A_log, D_skip, yB);
    // out_proj: x = xsrc + f;  then x += flip(r)
    gemm(stream, yB, 512, 0, xzB + 512, 1024,
         W_out, 0, nullptr, xsrc, x, 0,
         M_, 512, 256, 0, 0, N_, 0, 1.f, 0, 1);
    gemm(stream, yB + (long)M_ * 512, 512, 0, xzB + (long)M_ * 1024 + 512, 1024,
         W_out + 512 * 256, 0, nullptr, x, x, 0,
         M_, 512, 256, 0, 1, N_, 0, 1.f, 0, 1);
    // FFN
    ln_kernel<<<2048, 256, 0, stream>>>(x, ln2_g, ln2_b, xn);
    gemm(stream, xn, 256, 0, nullptr, 0, ffn_W1, 0, ffn_b1, nullptr,
         hB, 0, M_, 256, H_, 0, 0, N_, 1 /*silu*/, 1.f, 0, 1);
    gemm(stream, hB, 512, 0, nullptr, 0, ffn_W2, 0, ffn_b2, x,
         x, 0, M_, 512, 256, 0, 0, N_, 0, 1.f, 0, 1);
    xsrc = x;
  }

  // ---- graph stage ----
  sup_kernel<<<N_, 256, 0, stream>>>(node_emb, supB);
  // cheb2 = 2*sup@sup - I
  gemm(stream, supB, 512, 0, nullptr, 0, supB, 0, nullptr, nullptr,
       chebB, 0, N_, 512, 512, 0, 0, N_, 0, 2.f, 1, 1);
  // xg1[b] = sup @ x[b]; xg2[b] = cheb2 @ x[b]
  gemm(stream, supB, 512, 0, nullptr, 0, x, (long)N_ * D_, nullptr, nullptr,
       xg1, (long)N_ * D_, N_, 512, 256, 0, 0, N_, 0, 1.f, 0, B_);
  gemm(stream, chebB, 512, 0, nullptr, 0, x, (long)N_ * D_, nullptr, nullptr,
       xg2, (long)N_ * D_, N_, 512, 256, 0, 0, N_, 0, 1.f, 0, B_);
  // per-node pooled weights, 8 chunks of 64 nodes
  for (int c = 0; c < 8; ++c) {
    wn_chunk_kernel<<<dim3(768, 64), 256, 0, stream>>>(node_emb, weights_pool, WnB, c * 64);
    apply_wn_kernel<<<dim3(4, 64), 256, 0, stream>>>(x, xg1, xg2, WnB, node_emb,
                                                     bias_pool, x2B, c * 64);
  }
  // final projection
  gemm(stream, x2B, 256, 0, nullptr, 0, W_proj, 0, b_proj, nullptr,
       out, 0, M_, 256, P_, 0, 0, N_, 0, 1.f, 0, 1);
}